// Round 3
// baseline (196.922 us; speedup 1.0000x reference)
//
#include <hip/hip_runtime.h>
#include <hip/hip_bf16.h>
#include <stdint.h>

#define B_ 64
#define T_ 20
#define N_ 8192
#define E_ 128
#define H_ 128
#define G4 512
#define SPLITK 16

typedef short bf16x8 __attribute__((ext_vector_type(8)));
typedef float f32x4 __attribute__((ext_vector_type(4)));

__device__ __forceinline__ float sigmoidf_(float x){ return 1.0f/(1.0f+expf(-x)); }

__device__ __forceinline__ unsigned short f2bf(float f){
  union { float f; uint32_t u; } v; v.f = f;
  uint32_t u = v.u;
  uint32_t r = (u + 0x7FFFu + ((u >> 16) & 1u)) >> 16;
  return (unsigned short)r;
}
__device__ __forceinline__ uint32_t pk2(float a, float b){
  return (uint32_t)f2bf(a) | ((uint32_t)f2bf(b) << 16);
}
__device__ __forceinline__ float bf2f(unsigned short s){
  union { uint32_t u; float f; } v; v.u = ((uint32_t)s) << 16; return v.f;
}

// ---------------- 1. transpose W1,W2 -> W12T[n][0:128]=W1[:,n], [128:256]=W2[:,n]
__global__ void k_transpose(const float* __restrict__ W1, const float* __restrict__ W2,
                            float* __restrict__ W12T){
  __shared__ float t1[128][33];
  __shared__ float t2[128][33];
  int n0 = blockIdx.x * 32;
  int tid = threadIdx.x;           // 256
  int nl = tid & 31, eg = tid >> 5;
  for (int i = 0; i < 16; i++){
    int e = eg * 16 + i;
    t1[e][nl] = W1[(size_t)e*N_ + n0 + nl];
    t2[e][nl] = W2[(size_t)e*N_ + n0 + nl];
  }
  __syncthreads();
  for (int n = 0; n < 32; n++){
    float v = (tid < 128) ? t1[tid][n] : t2[tid-128][n];
    W12T[(size_t)(n0+n)*256 + tid] = v;
  }
}

// ---------------- 2. fused sparse MLP + x-projection
__global__ void k_mlpx(const float* __restrict__ x, const int* __restrict__ seq_len,
                       const float* __restrict__ W12T, const float* __restrict__ b1,
                       const float* __restrict__ b2, const float* __restrict__ W_ih,
                       const float* __restrict__ b_ih, const float* __restrict__ b_hh,
                       float* __restrict__ Xp){
  int bt = blockIdx.x;
  int b = bt / T_, t = bt % T_;
  if (t >= seq_len[b]) return;     // invalid steps never consumed downstream
  __shared__ int idxs[1024];
  __shared__ int cnt;
  __shared__ float e2s[128];
  __shared__ float bx[128];
  int tid = threadIdx.x;           // 256
  if (tid == 0) cnt = 0;
  __syncthreads();
  const float4* xr = (const float4*)(x + (size_t)bt * N_);
  for (int i = 0; i < 8; i++){
    float4 v = xr[i*256 + tid];
    int base = (i*256 + tid)*4;
    if (v.x != 0.f){ int q = atomicAdd(&cnt,1); idxs[q] = base;   }
    if (v.y != 0.f){ int q = atomicAdd(&cnt,1); idxs[q] = base+1; }
    if (v.z != 0.f){ int q = atomicAdd(&cnt,1); idxs[q] = base+2; }
    if (v.w != 0.f){ int q = atomicAdd(&cnt,1); idxs[q] = base+3; }
  }
  __syncthreads();
  int m = cnt; if (m > 1024) m = 1024;
  float acc = (tid < 128) ? b1[tid] : b2[tid-128];
  for (int i = 0; i < m; i++)
    acc += W12T[(size_t)idxs[i]*256 + tid];
  acc = fmaxf(acc, 0.f);
  if (tid >= 128) e2s[tid-128] = acc;
  __syncthreads();
  if (tid < 128) bx[tid] = fmaxf(acc, e2s[tid]);
  __syncthreads();
  #pragma unroll
  for (int half = 0; half < 2; half++){
    int j = half*256 + tid;
    const float4* wr = (const float4*)(W_ih + (size_t)j * E_);
    float s0 = b_ih[j] + b_hh[j], s1 = 0.f, s2 = 0.f, s3 = 0.f;
    #pragma unroll
    for (int k4 = 0; k4 < 32; k4 += 4){
      float4 w, h;
      w = wr[k4+0]; h = *(const float4*)&bx[k4*4+ 0]; s0 += w.x*h.x + w.y*h.y + w.z*h.z + w.w*h.w;
      w = wr[k4+1]; h = *(const float4*)&bx[k4*4+ 4]; s1 += w.x*h.x + w.y*h.y + w.z*h.z + w.w*h.w;
      w = wr[k4+2]; h = *(const float4*)&bx[k4*4+ 8]; s2 += w.x*h.x + w.y*h.y + w.z*h.z + w.w*h.w;
      w = wr[k4+3]; h = *(const float4*)&bx[k4*4+12]; s3 += w.x*h.x + w.y*h.y + w.z*h.z + w.w*h.w;
    }
    Xp[(size_t)bt*G4 + j] = (s0 + s1) + (s2 + s3);
  }
}

// ---------------- 3. LSTM: one block per batch row, W_hh row register-cached
__global__ void __launch_bounds__(512, 2)
k_lstm(const int* __restrict__ seq_len, const float* __restrict__ Xp,
       const float* __restrict__ W_hh, float* __restrict__ hn){
  int b = blockIdx.x;
  int L = seq_len[b];
  int j = threadIdx.x;             // 512
  float4 whh[32];
  const float4* wr = (const float4*)(W_hh + (size_t)j * H_);
  #pragma unroll
  for (int k = 0; k < 32; k++) whh[k] = wr[k];
  __shared__ float hs[128];
  __shared__ float gs[512];
  if (j < 128) hs[j] = 0.f;
  float c = 0.f;
  __syncthreads();
  for (int t = 0; t < L; t++){
    float s0 = Xp[((size_t)b*T_ + t)*G4 + j], s1 = 0.f, s2 = 0.f, s3 = 0.f;
    #pragma unroll
    for (int k = 0; k < 32; k += 4){
      float4 w, h;
      w = whh[k+0]; h = *(const float4*)&hs[k*4+ 0]; s0 += w.x*h.x + w.y*h.y + w.z*h.z + w.w*h.w;
      w = whh[k+1]; h = *(const float4*)&hs[k*4+ 4]; s1 += w.x*h.x + w.y*h.y + w.z*h.z + w.w*h.w;
      w = whh[k+2]; h = *(const float4*)&hs[k*4+ 8]; s2 += w.x*h.x + w.y*h.y + w.z*h.z + w.w*h.w;
      w = whh[k+3]; h = *(const float4*)&hs[k*4+12]; s3 += w.x*h.x + w.y*h.y + w.z*h.z + w.w*h.w;
    }
    gs[j] = (s0 + s1) + (s2 + s3);
    __syncthreads();
    if (j < 128){
      float i_ = gs[j], f_ = gs[128+j], gg = gs[256+j], o_ = gs[384+j];
      c = sigmoidf_(f_)*c + sigmoidf_(i_)*tanhf(gg);
      hs[j] = sigmoidf_(o_)*tanhf(c);
    }
    __syncthreads();
  }
  if (j < 128) hn[(size_t)b*H_ + j] = hs[j];
}

// ---------------- 4. p = sigmoid(hn @ W_out^T) via MFMA -> bf16 only
__global__ void k_pout(const float* __restrict__ hn, const float* __restrict__ W_out,
                       unsigned short* __restrict__ pbf){
  __shared__ unsigned short hb[64*128];   // bf16, XOR-swizzled 16B blocks
  int tid = threadIdx.x;                  // 256
  {
    int row = tid >> 2;
    int k16 = (tid & 3) * 32;
    const float4* hr = (const float4*)(hn + (size_t)row*H_ + k16);
    #pragma unroll
    for (int i = 0; i < 4; i++){
      float4 a = hr[i*2], bq = hr[i*2+1];
      uint4 u; u.x = pk2(a.x,a.y); u.y = pk2(a.z,a.w); u.z = pk2(bq.x,bq.y); u.w = pk2(bq.z,bq.w);
      int blk = (k16 >> 3) + i;
      *(uint4*)&hb[row*128 + ((blk ^ (row & 7)) * 8)] = u;
    }
  }
  __syncthreads();
  int w = tid >> 6, l = tid & 63;
  int n0 = blockIdx.x * 128;
  f32x4 acc[8];
  #pragma unroll
  for (int i = 0; i < 8; i++) acc[i] = (f32x4){0.f,0.f,0.f,0.f};
  int row = w*16 + (l & 15);
  #pragma unroll
  for (int ks = 0; ks < 4; ks++){
    int kk = ks*32 + (l >> 4)*8;
    int blk = kk >> 3;
    bf16x8 af = *(bf16x8*)&hb[row*128 + ((blk ^ (row & 7)) * 8)];
    #pragma unroll
    for (int nt = 0; nt < 8; nt++){
      int n = n0 + nt*16 + (l & 15);
      const float4* wp = (const float4*)(W_out + (size_t)n*H_ + kk);
      float4 wa = wp[0], wb = wp[1];
      union { uint4 u; bf16x8 v; } cc;
      cc.u.x = pk2(wa.x,wa.y); cc.u.y = pk2(wa.z,wa.w);
      cc.u.z = pk2(wb.x,wb.y); cc.u.w = pk2(wb.z,wb.w);
      acc[nt] = __builtin_amdgcn_mfma_f32_16x16x32_bf16(af, cc.v, acc[nt], 0, 0, 0);
    }
  }
  #pragma unroll
  for (int nt = 0; nt < 8; nt++){
    int n = n0 + nt*16 + (l & 15);
    #pragma unroll
    for (int r = 0; r < 4; r++){
      int rr = w*16 + (l >> 4)*4 + r;
      float pv = 1.f/(1.f + expf(-acc[nt][r]));
      pbf[(size_t)rr*N_ + n] = f2bf(pv);
    }
  }
}

// ---------------- 5. Cp[s] = p @ A[ks-slice]  (split-K 16, NO atomics)
__global__ void __launch_bounds__(256, 4)
k_gemm(const unsigned short* __restrict__ pbf, const float* __restrict__ Ag,
       float* __restrict__ Cp){
  __shared__ unsigned short Abf[128*32];  // [n][k] bf16, k4^((n&3)*8) swizzle
  __shared__ unsigned short pt[64*32];    // [b][k] bf16 linear
  int tid = threadIdx.x;                  // 256
  int nb = blockIdx.x & 63, ks = blockIdx.x >> 6;
  int n0 = nb * 128;
  int kbase = ks * (N_ / SPLITK);
  int w = tid >> 6, l = tid & 63;
  f32x4 acc[8];
  #pragma unroll
  for (int i = 0; i < 8; i++) acc[i] = (f32x4){0.f,0.f,0.f,0.f};
  int sn = tid & 127, kq = tid >> 7;
  int prow = tid >> 2, phw = (tid & 3) * 8;
  float* Cout = Cp + (size_t)ks * (B_ * N_);

  for (int step = 0; step < (N_ / SPLITK) / 32; step++){
    int kb = kbase + step*32;
    *(uint4*)&pt[prow*32 + phw] = *(const uint4*)&pbf[(size_t)prow*N_ + kb + phw];
    #pragma unroll
    for (int i = 0; i < 4; i++){
      int k4 = kq*16 + i*4;
      float v0 = Ag[(size_t)(kb + k4 + 0)*N_ + n0 + sn];
      float v1 = Ag[(size_t)(kb + k4 + 1)*N_ + n0 + sn];
      float v2 = Ag[(size_t)(kb + k4 + 2)*N_ + n0 + sn];
      float v3 = Ag[(size_t)(kb + k4 + 3)*N_ + n0 + sn];
      uint2 u; u.x = pk2(v0,v1); u.y = pk2(v2,v3);
      *(uint2*)&Abf[sn*32 + (k4 ^ ((sn & 3) * 8))] = u;
    }
    __syncthreads();
    bf16x8 af = *(bf16x8*)&pt[(w*16 + (l & 15))*32 + (l >> 4)*8];
    #pragma unroll
    for (int nt = 0; nt < 8; nt++){
      int n = nt*16 + (l & 15);
      bf16x8 bfr = *(bf16x8*)&Abf[n*32 + (((l >> 4)*8) ^ ((n & 3)*8))];
      acc[nt] = __builtin_amdgcn_mfma_f32_16x16x32_bf16(af, bfr, acc[nt], 0, 0, 0);
    }
    __syncthreads();
  }
  #pragma unroll
  for (int nt = 0; nt < 8; nt++){
    int n = n0 + nt*16 + (l & 15);
    #pragma unroll
    for (int r = 0; r < 4; r++){
      int rr = w*16 + (l >> 4)*4 + r;
      Cout[(size_t)rr*N_ + n] = acc[nt][r];
    }
  }
}

// ---------------- 6. final blend: sum split-K partials + blend (p read as bf16)
__global__ void k_final(const unsigned short* __restrict__ pbf, const float* __restrict__ Cp,
                        const float* __restrict__ I_B, float* __restrict__ out){
  int idx = blockIdx.x*256 + threadIdx.x;
  ushort4 pu = ((const ushort4*)pbf)[idx];
  float4 cv = {0.f, 0.f, 0.f, 0.f};
  #pragma unroll
  for (int s = 0; s < SPLITK; s++){
    float4 v = ((const float4*)(Cp + (size_t)s * (B_ * N_)))[idx];
    cv.x += v.x; cv.y += v.y; cv.z += v.z; cv.w += v.w;
  }
  int n = (idx*4) & (N_-1);
  float4 ib = *(const float4*)&I_B[n];
  float4 o;
  float p0 = bf2f(pu.x), p1 = bf2f(pu.y), p2 = bf2f(pu.z), p3 = bf2f(pu.w);
  o.x = 0.5f*p0 + 0.5f*(p0*fmaxf(ib.x,0.f) + fmaxf(cv.x,0.f));
  o.y = 0.5f*p1 + 0.5f*(p1*fmaxf(ib.y,0.f) + fmaxf(cv.y,0.f));
  o.z = 0.5f*p2 + 0.5f*(p2*fmaxf(ib.z,0.f) + fmaxf(cv.z,0.f));
  o.w = 0.5f*p3 + 0.5f*(p3*fmaxf(ib.w,0.f) + fmaxf(cv.w,0.f));
  ((float4*)out)[idx] = o;
}

extern "C" void kernel_launch(void* const* d_in, const int* in_sizes, int n_in,
                              void* d_out, int out_size, void* d_ws, size_t ws_size,
                              hipStream_t stream) {
  const float* x     = (const float*)d_in[0];
  const int*   seq   = (const int*)  d_in[1];
  const float* A     = (const float*)d_in[2];
  const float* W1    = (const float*)d_in[3];
  const float* b1    = (const float*)d_in[4];
  const float* W2    = (const float*)d_in[5];
  const float* b2    = (const float*)d_in[6];
  const float* W_ih  = (const float*)d_in[7];
  const float* W_hh  = (const float*)d_in[8];
  const float* b_ih  = (const float*)d_in[9];
  const float* b_hh  = (const float*)d_in[10];
  const float* W_out = (const float*)d_in[11];
  const float* I_B   = (const float*)d_in[12];
  float* out = (float*)d_out;

  float* ws     = (float*)d_ws;
  float* W12T   = ws;                        // 8192*256        = 2,097,152 f
  float* Xp     = W12T + 2097152;            // 1280*512        =   655,360 f
  float* hn     = Xp + 655360;               // 64*128          =     8,192 f
  float* Cp     = hn + 8192;                 // 16*64*8192      = 8,388,608 f
  unsigned short* pbf = (unsigned short*)(Cp + 8388608); // 64*8192 bf16

  k_transpose<<<256, 256, 0, stream>>>(W1, W2, W12T);
  k_mlpx     <<<1280,256, 0, stream>>>(x, seq, W12T, b1, b2, W_ih, b_ih, b_hh, Xp);
  k_lstm     <<<64,  512, 0, stream>>>(seq, Xp, W_hh, hn);
  k_pout     <<<64,  256, 0, stream>>>(hn, W_out, pbf);
  k_gemm     <<<64*SPLITK, 256, 0, stream>>>(pbf, A, Cp);
  k_final    <<<512, 256, 0, stream>>>(pbf, Cp, I_B, out);
}

// Round 4
// 175.060 us; speedup vs baseline: 1.1249x; 1.1249x over previous
//
#include <hip/hip_runtime.h>
#include <hip/hip_bf16.h>
#include <stdint.h>

#define B_ 64
#define T_ 20
#define N_ 8192
#define E_ 128
#define H_ 128
#define G4 512
#define SPLITK 16

typedef short bf16x8 __attribute__((ext_vector_type(8)));
typedef float f32x4 __attribute__((ext_vector_type(4)));

__device__ __forceinline__ float sigmoidf_(float x){ return 1.0f/(1.0f+expf(-x)); }

__device__ __forceinline__ unsigned short f2bf(float f){
  union { float f; uint32_t u; } v; v.f = f;
  uint32_t u = v.u;
  uint32_t r = (u + 0x7FFFu + ((u >> 16) & 1u)) >> 16;
  return (unsigned short)r;
}
__device__ __forceinline__ uint32_t pk2(float a, float b){
  return (uint32_t)f2bf(a) | ((uint32_t)f2bf(b) << 16);
}
__device__ __forceinline__ float bf2f(unsigned short s){
  union { uint32_t u; float f; } v; v.u = ((uint32_t)s) << 16; return v.f;
}

// ---------------- 1. transpose W1,W2 -> W12T[n][0:128]=W1[:,n], [128:256]=W2[:,n]
__global__ void k_transpose(const float* __restrict__ W1, const float* __restrict__ W2,
                            float* __restrict__ W12T){
  __shared__ float t1[128][33];
  __shared__ float t2[128][33];
  int n0 = blockIdx.x * 32;
  int tid = threadIdx.x;           // 256
  int nl = tid & 31, eg = tid >> 5;
  for (int i = 0; i < 16; i++){
    int e = eg * 16 + i;
    t1[e][nl] = W1[(size_t)e*N_ + n0 + nl];
    t2[e][nl] = W2[(size_t)e*N_ + n0 + nl];
  }
  __syncthreads();
  for (int n = 0; n < 32; n++){
    float v = (tid < 128) ? t1[tid][n] : t2[tid-128][n];
    W12T[(size_t)(n0+n)*256 + tid] = v;
  }
}

// ---------------- 2. fused sparse MLP + x-projection
__global__ void k_mlpx(const float* __restrict__ x, const int* __restrict__ seq_len,
                       const float* __restrict__ W12T, const float* __restrict__ b1,
                       const float* __restrict__ b2, const float* __restrict__ W_ih,
                       const float* __restrict__ b_ih, const float* __restrict__ b_hh,
                       float* __restrict__ Xp){
  int bt = blockIdx.x;
  int b = bt / T_, t = bt % T_;
  if (t >= seq_len[b]) return;     // invalid steps never consumed downstream
  __shared__ int idxs[1024];
  __shared__ int cnt;
  __shared__ float e2s[128];
  __shared__ float bx[128];
  int tid = threadIdx.x;           // 256
  if (tid == 0) cnt = 0;
  __syncthreads();
  const float4* xr = (const float4*)(x + (size_t)bt * N_);
  for (int i = 0; i < 8; i++){
    float4 v = xr[i*256 + tid];
    int base = (i*256 + tid)*4;
    if (v.x != 0.f){ int q = atomicAdd(&cnt,1); idxs[q] = base;   }
    if (v.y != 0.f){ int q = atomicAdd(&cnt,1); idxs[q] = base+1; }
    if (v.z != 0.f){ int q = atomicAdd(&cnt,1); idxs[q] = base+2; }
    if (v.w != 0.f){ int q = atomicAdd(&cnt,1); idxs[q] = base+3; }
  }
  __syncthreads();
  int m = cnt; if (m > 1024) m = 1024;
  float acc = (tid < 128) ? b1[tid] : b2[tid-128];
  for (int i = 0; i < m; i++)
    acc += W12T[(size_t)idxs[i]*256 + tid];
  acc = fmaxf(acc, 0.f);
  if (tid >= 128) e2s[tid-128] = acc;
  __syncthreads();
  if (tid < 128) bx[tid] = fmaxf(acc, e2s[tid]);
  __syncthreads();
  #pragma unroll
  for (int half = 0; half < 2; half++){
    int j = half*256 + tid;
    const float4* wr = (const float4*)(W_ih + (size_t)j * E_);
    float s0 = b_ih[j] + b_hh[j], s1 = 0.f, s2 = 0.f, s3 = 0.f;
    #pragma unroll
    for (int k4 = 0; k4 < 32; k4 += 4){
      float4 w, h;
      w = wr[k4+0]; h = *(const float4*)&bx[k4*4+ 0]; s0 += w.x*h.x + w.y*h.y + w.z*h.z + w.w*h.w;
      w = wr[k4+1]; h = *(const float4*)&bx[k4*4+ 4]; s1 += w.x*h.x + w.y*h.y + w.z*h.z + w.w*h.w;
      w = wr[k4+2]; h = *(const float4*)&bx[k4*4+ 8]; s2 += w.x*h.x + w.y*h.y + w.z*h.z + w.w*h.w;
      w = wr[k4+3]; h = *(const float4*)&bx[k4*4+12]; s3 += w.x*h.x + w.y*h.y + w.z*h.z + w.w*h.w;
    }
    Xp[(size_t)bt*G4 + j] = (s0 + s1) + (s2 + s3);
  }
}

// ---------------- 3. LSTM: one block per batch row, W_hh row register-cached
__global__ void __launch_bounds__(512, 2)
k_lstm(const int* __restrict__ seq_len, const float* __restrict__ Xp,
       const float* __restrict__ W_hh, float* __restrict__ hn){
  int b = blockIdx.x;
  int L = seq_len[b];
  int j = threadIdx.x;             // 512
  float4 whh[32];
  const float4* wr = (const float4*)(W_hh + (size_t)j * H_);
  #pragma unroll
  for (int k = 0; k < 32; k++) whh[k] = wr[k];
  __shared__ float hs[128];
  __shared__ float gs[512];
  if (j < 128) hs[j] = 0.f;
  float c = 0.f;
  __syncthreads();
  for (int t = 0; t < L; t++){
    float s0 = Xp[((size_t)b*T_ + t)*G4 + j], s1 = 0.f, s2 = 0.f, s3 = 0.f;
    #pragma unroll
    for (int k = 0; k < 32; k += 4){
      float4 w, h;
      w = whh[k+0]; h = *(const float4*)&hs[k*4+ 0]; s0 += w.x*h.x + w.y*h.y + w.z*h.z + w.w*h.w;
      w = whh[k+1]; h = *(const float4*)&hs[k*4+ 4]; s1 += w.x*h.x + w.y*h.y + w.z*h.z + w.w*h.w;
      w = whh[k+2]; h = *(const float4*)&hs[k*4+ 8]; s2 += w.x*h.x + w.y*h.y + w.z*h.z + w.w*h.w;
      w = whh[k+3]; h = *(const float4*)&hs[k*4+12]; s3 += w.x*h.x + w.y*h.y + w.z*h.z + w.w*h.w;
    }
    gs[j] = (s0 + s1) + (s2 + s3);
    __syncthreads();
    if (j < 128){
      float i_ = gs[j], f_ = gs[128+j], gg = gs[256+j], o_ = gs[384+j];
      c = sigmoidf_(f_)*c + sigmoidf_(i_)*tanhf(gg);
      hs[j] = sigmoidf_(o_)*tanhf(c);
    }
    __syncthreads();
  }
  if (j < 128) hn[(size_t)b*H_ + j] = hs[j];
}

// ---------------- 4. p = sigmoid(hn @ W_out^T) via MFMA -> bf16 only
__global__ void k_pout(const float* __restrict__ hn, const float* __restrict__ W_out,
                       unsigned short* __restrict__ pbf){
  __shared__ unsigned short hb[64*128];   // bf16, XOR-swizzled 16B blocks
  int tid = threadIdx.x;                  // 256
  {
    int row = tid >> 2;
    int k16 = (tid & 3) * 32;
    const float4* hr = (const float4*)(hn + (size_t)row*H_ + k16);
    #pragma unroll
    for (int i = 0; i < 4; i++){
      float4 a = hr[i*2], bq = hr[i*2+1];
      uint4 u; u.x = pk2(a.x,a.y); u.y = pk2(a.z,a.w); u.z = pk2(bq.x,bq.y); u.w = pk2(bq.z,bq.w);
      int blk = (k16 >> 3) + i;
      *(uint4*)&hb[row*128 + ((blk ^ (row & 7)) * 8)] = u;
    }
  }
  __syncthreads();
  int w = tid >> 6, l = tid & 63;
  int n0 = blockIdx.x * 128;
  f32x4 acc[8];
  #pragma unroll
  for (int i = 0; i < 8; i++) acc[i] = (f32x4){0.f,0.f,0.f,0.f};
  int row = w*16 + (l & 15);
  #pragma unroll
  for (int ks = 0; ks < 4; ks++){
    int kk = ks*32 + (l >> 4)*8;
    int blk = kk >> 3;
    bf16x8 af = *(bf16x8*)&hb[row*128 + ((blk ^ (row & 7)) * 8)];
    #pragma unroll
    for (int nt = 0; nt < 8; nt++){
      int n = n0 + nt*16 + (l & 15);
      const float4* wp = (const float4*)(W_out + (size_t)n*H_ + kk);
      float4 wa = wp[0], wb = wp[1];
      union { uint4 u; bf16x8 v; } cc;
      cc.u.x = pk2(wa.x,wa.y); cc.u.y = pk2(wa.z,wa.w);
      cc.u.z = pk2(wb.x,wb.y); cc.u.w = pk2(wb.z,wb.w);
      acc[nt] = __builtin_amdgcn_mfma_f32_16x16x32_bf16(af, cc.v, acc[nt], 0, 0, 0);
    }
  }
  #pragma unroll
  for (int nt = 0; nt < 8; nt++){
    int n = n0 + nt*16 + (l & 15);
    #pragma unroll
    for (int r = 0; r < 4; r++){
      int rr = w*16 + (l >> 4)*4 + r;
      float pv = 1.f/(1.f + expf(-acc[nt][r]));
      pbf[(size_t)rr*N_ + n] = f2bf(pv);
    }
  }
}

// ---------------- 5. Cp[s] = p @ A[ks-slice]  (split-K 16, dbuf + raw barrier pipeline)
__global__ void __launch_bounds__(256, 3)
k_gemm(const unsigned short* __restrict__ pbf, const float* __restrict__ Ag,
       float* __restrict__ Cp){
  __shared__ unsigned short Abf[2][128*32];  // [n][k] bf16, k4^((n&3)*8) swizzle
  __shared__ unsigned short pt[2][64*32];    // [b][k] bf16 linear
  int tid = threadIdx.x;                     // 256
  int nb = blockIdx.x & 63, ks = blockIdx.x >> 6;
  int n0 = nb * 128;
  int kbase = ks * (N_ / SPLITK);
  int w = tid >> 6, l = tid & 63;
  f32x4 acc[8];
  #pragma unroll
  for (int i = 0; i < 8; i++) acc[i] = (f32x4){0.f,0.f,0.f,0.f};
  int sn = tid & 127, kq = tid >> 7;
  int prow = tid >> 2, phw = (tid & 3) * 8;
  float* Cout = Cp + (size_t)ks * (B_ * N_);
  const int NSTEP = (N_ / SPLITK) / 32;      // 16 (even)

  float aA[16], aB[16];
  uint4 pA, pB;

  // issue global loads for one 32-wide k-chunk into a register set
  auto issue = [&](float* ar, uint4& pr, int kb) {
    pr = *(const uint4*)&pbf[(size_t)prow*N_ + kb + phw];
    #pragma unroll
    for (int i = 0; i < 4; i++){
      int k4 = kq*16 + i*4;
      const float* base = Ag + (size_t)(kb + k4)*N_ + n0 + sn;
      ar[i*4+0] = __builtin_nontemporal_load(base);
      ar[i*4+1] = __builtin_nontemporal_load(base + (size_t)N_);
      ar[i*4+2] = __builtin_nontemporal_load(base + (size_t)2*N_);
      ar[i*4+3] = __builtin_nontemporal_load(base + (size_t)3*N_);
    }
  };
  // convert + write a register set into LDS buffer `buf` (compile-time)
  auto stage = [&](int buf, const float* ar, const uint4& pr) {
    *(uint4*)&pt[buf][prow*32 + phw] = pr;
    #pragma unroll
    for (int i = 0; i < 4; i++){
      int k4 = kq*16 + i*4;
      uint2 u; u.x = pk2(ar[i*4+0], ar[i*4+1]); u.y = pk2(ar[i*4+2], ar[i*4+3]);
      *(uint2*)&Abf[buf][sn*32 + (k4 ^ ((sn & 3) * 8))] = u;
    }
  };
  auto compute = [&](int buf) {
    bf16x8 af = *(bf16x8*)&pt[buf][(w*16 + (l & 15))*32 + (l >> 4)*8];
    #pragma unroll
    for (int nt = 0; nt < 8; nt++){
      int n = nt*16 + (l & 15);
      bf16x8 bfr = *(bf16x8*)&Abf[buf][n*32 + (((l >> 4)*8) ^ ((n & 3)*8))];
      acc[nt] = __builtin_amdgcn_mfma_f32_16x16x32_bf16(af, bfr, acc[nt], 0, 0, 0);
    }
  };

  issue(aA, pA, kbase);
  for (int s = 0; s < NSTEP; s += 2){
    // even step: consume set A -> buf 0
    if (s + 1 < NSTEP) issue(aB, pB, kbase + (s+1)*32);
    stage(0, aA, pA);                                // waits (counted) on set-A loads only
    asm volatile("s_waitcnt lgkmcnt(0)" ::: "memory");
    __builtin_amdgcn_sched_barrier(0);
    __builtin_amdgcn_s_barrier();                    // raw barrier: no vmcnt drain
    __builtin_amdgcn_sched_barrier(0);
    compute(0);
    // odd step: consume set B -> buf 1
    if (s + 2 < NSTEP) issue(aA, pA, kbase + (s+2)*32);
    stage(1, aB, pB);
    asm volatile("s_waitcnt lgkmcnt(0)" ::: "memory");
    __builtin_amdgcn_sched_barrier(0);
    __builtin_amdgcn_s_barrier();
    __builtin_amdgcn_sched_barrier(0);
    compute(1);
  }

  #pragma unroll
  for (int nt = 0; nt < 8; nt++){
    int n = n0 + nt*16 + (l & 15);
    #pragma unroll
    for (int r = 0; r < 4; r++){
      int rr = w*16 + (l >> 4)*4 + r;
      Cout[(size_t)rr*N_ + n] = acc[nt][r];
    }
  }
}

// ---------------- 6. final blend: sum split-K partials + blend (p read as bf16)
__global__ void k_final(const unsigned short* __restrict__ pbf, const float* __restrict__ Cp,
                        const float* __restrict__ I_B, float* __restrict__ out){
  int idx = blockIdx.x*256 + threadIdx.x;
  ushort4 pu = ((const ushort4*)pbf)[idx];
  float4 cv = {0.f, 0.f, 0.f, 0.f};
  #pragma unroll
  for (int s = 0; s < SPLITK; s++){
    float4 v = ((const float4*)(Cp + (size_t)s * (B_ * N_)))[idx];
    cv.x += v.x; cv.y += v.y; cv.z += v.z; cv.w += v.w;
  }
  int n = (idx*4) & (N_-1);
  float4 ib = *(const float4*)&I_B[n];
  float4 o;
  float p0 = bf2f(pu.x), p1 = bf2f(pu.y), p2 = bf2f(pu.z), p3 = bf2f(pu.w);
  o.x = 0.5f*p0 + 0.5f*(p0*fmaxf(ib.x,0.f) + fmaxf(cv.x,0.f));
  o.y = 0.5f*p1 + 0.5f*(p1*fmaxf(ib.y,0.f) + fmaxf(cv.y,0.f));
  o.z = 0.5f*p2 + 0.5f*(p2*fmaxf(ib.z,0.f) + fmaxf(cv.z,0.f));
  o.w = 0.5f*p3 + 0.5f*(p3*fmaxf(ib.w,0.f) + fmaxf(cv.w,0.f));
  ((float4*)out)[idx] = o;
}

extern "C" void kernel_launch(void* const* d_in, const int* in_sizes, int n_in,
                              void* d_out, int out_size, void* d_ws, size_t ws_size,
                              hipStream_t stream) {
  const float* x     = (const float*)d_in[0];
  const int*   seq   = (const int*)  d_in[1];
  const float* A     = (const float*)d_in[2];
  const float* W1    = (const float*)d_in[3];
  const float* b1    = (const float*)d_in[4];
  const float* W2    = (const float*)d_in[5];
  const float* b2    = (const float*)d_in[6];
  const float* W_ih  = (const float*)d_in[7];
  const float* W_hh  = (const float*)d_in[8];
  const float* b_ih  = (const float*)d_in[9];
  const float* b_hh  = (const float*)d_in[10];
  const float* W_out = (const float*)d_in[11];
  const float* I_B   = (const float*)d_in[12];
  float* out = (float*)d_out;

  float* ws     = (float*)d_ws;
  float* W12T   = ws;                        // 8192*256        = 2,097,152 f
  float* Xp     = W12T + 2097152;            // 1280*512        =   655,360 f
  float* hn     = Xp + 655360;               // 64*128          =     8,192 f
  float* Cp     = hn + 8192;                 // 16*64*8192      = 8,388,608 f
  unsigned short* pbf = (unsigned short*)(Cp + 8388608); // 64*8192 bf16

  k_transpose<<<256, 256, 0, stream>>>(W1, W2, W12T);
  k_mlpx     <<<1280,256, 0, stream>>>(x, seq, W12T, b1, b2, W_ih, b_ih, b_hh, Xp);
  k_lstm     <<<64,  512, 0, stream>>>(seq, Xp, W_hh, hn);
  k_pout     <<<64,  256, 0, stream>>>(hn, W_out, pbf);
  k_gemm     <<<64*SPLITK, 256, 0, stream>>>(pbf, A, Cp);
  k_final    <<<512, 256, 0, stream>>>(pbf, Cp, I_B, out);
}